// Round 3
// baseline (2097.996 us; speedup 1.0000x reference)
//
#include <hip/hip_runtime.h>
#include <hip/hip_bf16.h>
#include <stdint.h>

#define NB 64
#define NN 1024
#define NH 128
#define NS 12
#define BN (NB*NN)
#define D0 129
#define K0P 416
#define K1 768
#define NG 512
#define MAXNNZ 128
#define CH 16384
#define NCHUNK (BN/CH)

typedef __hip_bfloat16 bf16;
typedef float v4f __attribute__((ext_vector_type(4)));
typedef __bf16 v8bf __attribute__((ext_vector_type(8)));

__device__ __forceinline__ float bf2f(bf16 x) { return __bfloat162float(x); }
__device__ __forceinline__ bf16 f2bf(float x) { return __float2bfloat16(x); }
__device__ __forceinline__ float sane(float x) { return __builtin_isfinite(x) ? x : 0.f; }

// flagged load/store: f32 ? float data : bf16 data (flag is uniform per launch)
__device__ __forceinline__ float loadF(const void* p, size_t i, int f32) {
  return f32 ? ((const float*)p)[i] : bf2f(((const bf16*)p)[i]);
}
__device__ __forceinline__ void storeF(void* p, size_t i, float v, int f32) {
  if (f32) ((float*)p)[i] = v; else ((bf16*)p)[i] = f2bf(v);
}
__device__ __forceinline__ v8bf load8(const void* p, size_t i, int f32) {
  v8bf r;
  if (f32) {
    const float* fp = (const float*)p + i;
#pragma unroll
    for (int j = 0; j < 8; ++j) r[j] = (__bf16)fp[j];
  } else {
    r = *(const v8bf*)((const bf16*)p + i);
  }
  return r;
}

// dtype detector on ~N(0,1) probe: bf16 data -> even uint16s are real bf16
// (exponent 117..131 or zero); f32 data -> even uint16s are mantissa halves
// (uniform exponent bits -> mostly outside that window).
__global__ void detect_dtype(const unsigned short* __restrict__ probe, int* __restrict__ flag) {
  int t = threadIdx.x;
  unsigned short x = probe[2 * t];
  int e = (x >> 7) & 0xFF;
  int insane = !((x & 0x7FFF) == 0 || (e >= 117 && e <= 131));
  __shared__ int cnt;
  if (t == 0) cnt = 0;
  __syncthreads();
  atomicAdd(&cnt, insane);
  __syncthreads();
  if (t == 0) *flag = (cnt > 64) ? 1 : 0;
}

__global__ void build_csr(const void* __restrict__ sup, int* __restrict__ cols,
                          float* __restrict__ vals, int* __restrict__ cnt,
                          const int* __restrict__ flag) {
  int f32 = *flag;
  int n = blockIdx.x;
  __shared__ int cn;
  if (threadIdx.x == 0) cn = 0;
  __syncthreads();
  for (int m = threadIdx.x; m < NN; m += blockDim.x) {
    float v = loadF(sup, (size_t)n * NN + m, f32);
    if (v != 0.0f && __builtin_isfinite(v)) {
      int slot = atomicAdd(&cn, 1);
      if (slot < MAXNNZ) { cols[n * MAXNNZ + slot] = m; vals[n * MAXNNZ + slot] = v; }
    }
  }
  __syncthreads();
  if (threadIdx.x == 0) cnt[n] = (cn < MAXNNZ) ? cn : MAXNNZ;
}

__global__ void pack_wt(const void* __restrict__ w, bf16* __restrict__ bt,
                        int K, int Kp, int Nn, const int* __restrict__ flag) {
  int f32 = *flag;
  int n = blockIdx.x;
  for (int k = threadIdx.x; k < Kp; k += blockDim.x) {
    float v = (k < K) ? loadF(w, (size_t)k * Nn + n, f32) : 0.0f;
    bt[(size_t)n * Kp + k] = f2bf(v);
  }
}

// ---- layer 0 diffusion; R = chunk row offset (chunks are whole batches) ----
__global__ void diffuse0_a(const void* __restrict__ xin, const void* __restrict__ h0,
                           const int* __restrict__ cols, const float* __restrict__ vals,
                           const int* __restrict__ cnt, bf16* __restrict__ feats,
                           const int* __restrict__ flag, int R) {
  int f32 = *flag;
  int bn = R + blockIdx.x;
  int lbn = blockIdx.x;
  int n = bn & (NN - 1);
  int b = bn >> 10;
  int d = threadIdx.x;
  bf16* frow = feats + (size_t)lbn * K0P;
  if (d < D0) {
    float x0 = (d == 0) ? loadF(xin, bn, f32) : loadF(h0, (size_t)bn * NH + d - 1, f32);
    frow[d] = f2bf(x0);
    float acc = 0.f;
    int c = cnt[n];
    for (int j = 0; j < c; ++j) {
      int m = cols[n * MAXNNZ + j];
      float s = vals[n * MAXNNZ + j];
      int bm = (b << 10) | m;
      float xv = (d == 0) ? loadF(xin, bm, f32) : loadF(h0, (size_t)bm * NH + d - 1, f32);
      acc += s * xv;
    }
    frow[D0 + d] = f2bf(acc);
  } else if (d < D0 + (K0P - 3 * D0)) {
    frow[3 * D0 + (d - D0)] = f2bf(0.f);
  }
}

__global__ void diffuse0_b(const void* __restrict__ xin, const void* __restrict__ h0,
                           const int* __restrict__ cols, const float* __restrict__ vals,
                           const int* __restrict__ cnt, bf16* __restrict__ feats,
                           const int* __restrict__ flag, int R) {
  int f32 = *flag;
  int bn = R + blockIdx.x;
  int lbn = blockIdx.x;
  int n = bn & (NN - 1);
  int b = bn >> 10;
  int d = threadIdx.x;
  if (d >= D0) return;
  float x0 = (d == 0) ? loadF(xin, bn, f32) : loadF(h0, (size_t)bn * NH + d - 1, f32);
  float acc = -x0;
  int c = cnt[n];
  for (int j = 0; j < c; ++j) {
    int m = cols[n * MAXNNZ + j];
    float s = vals[n * MAXNNZ + j];
    int lbm = ((b << 10) | m) - R;
    float x1 = bf2f(feats[(size_t)lbm * K0P + D0 + d]);
    acc += 2.f * s * x1;
  }
  feats[(size_t)lbn * K0P + 2 * D0 + d] = f2bf(acc);
}

// ---- layer 1 diffusion: hs0 in d_out at element offset offH0; h1 = hidden at
//      element offset offH1in (= BN*NH). ----
__global__ void diffuse1_a(const void* __restrict__ dout, size_t offH0,
                           const void* __restrict__ hidden, size_t offH1in,
                           const int* __restrict__ cols, const float* __restrict__ vals,
                           const int* __restrict__ cnt, bf16* __restrict__ feats,
                           const int* __restrict__ flag, int R) {
  int f32 = *flag;
  int bn = R + blockIdx.x;
  int lbn = blockIdx.x;
  int n = bn & (NN - 1);
  int b = bn >> 10;
  int d = threadIdx.x;   // 0..255
  bf16* frow = feats + (size_t)lbn * K1;
  float x0 = (d < NH) ? loadF(dout, offH0 + (size_t)bn * NH + d, f32)
                      : loadF(hidden, offH1in + (size_t)bn * NH + d - NH, f32);
  frow[d] = f2bf(x0);
  float acc = 0.f;
  int c = cnt[n];
  for (int j = 0; j < c; ++j) {
    int m = cols[n * MAXNNZ + j];
    float s = vals[n * MAXNNZ + j];
    size_t bm = (size_t)((b << 10) | m) * NH;
    float xv = (d < NH) ? loadF(dout, offH0 + bm + d, f32)
                        : loadF(hidden, offH1in + bm + d - NH, f32);
    acc += s * xv;
  }
  frow[256 + d] = f2bf(acc);
}

__global__ void diffuse1_b(const void* __restrict__ dout, size_t offH0,
                           const void* __restrict__ hidden, size_t offH1in,
                           const int* __restrict__ cols, const float* __restrict__ vals,
                           const int* __restrict__ cnt, bf16* __restrict__ feats,
                           const int* __restrict__ flag, int R) {
  int f32 = *flag;
  int bn = R + blockIdx.x;
  int lbn = blockIdx.x;
  int n = bn & (NN - 1);
  int b = bn >> 10;
  int d = threadIdx.x;
  float x0 = (d < NH) ? loadF(dout, offH0 + (size_t)bn * NH + d, f32)
                      : loadF(hidden, offH1in + (size_t)bn * NH + d - NH, f32);
  float acc = -x0;
  int c = cnt[n];
  for (int j = 0; j < c; ++j) {
    int m = cols[n * MAXNNZ + j];
    float s = vals[n * MAXNNZ + j];
    int lbm = ((b << 10) | m) - R;
    float x1 = bf2f(feats[(size_t)lbm * K1 + 256 + d]);
    acc += 2.f * s * x1;
  }
  feats[(size_t)lbn * K1 + 512 + d] = f2bf(acc);
}

// ---- MFMA GEMM: gates(CHx512) = feats(CHxKd) * Bt(512xKd)^T + bias ----
__global__ __launch_bounds__(256) void gemm_bt(const bf16* __restrict__ A,
    const bf16* __restrict__ Bt, const void* __restrict__ bias,
    bf16* __restrict__ C, int Kd, const int* __restrict__ flag) {
  int f32 = *flag;
  __shared__ __align__(16) unsigned short As[128 * 32];
  __shared__ __align__(16) unsigned short Bs[128 * 32];
  const int tid = threadIdx.x;
  const int l = tid & 63;
  const int w = tid >> 6;
  const int wm = w >> 1, wn = w & 1;
  const int m0 = blockIdx.x * 128;
  const int n0 = blockIdx.y * 128;
  const bf16* Ab = A + (size_t)m0 * Kd;
  const bf16* Bb = Bt + (size_t)n0 * Kd;
  const int lr = l & 15, q = l >> 4;
  v4f acc[4][4] = {};
  for (int k0 = 0; k0 < Kd; k0 += 32) {
    v8bf ga[2], gb[2];
#pragma unroll
    for (int t = 0; t < 2; ++t) {
      int s = tid + 256 * t;
      int row = s >> 2, col = (s & 3) * 8;
      ga[t] = *(const v8bf*)(Ab + (size_t)row * Kd + k0 + col);
      gb[t] = *(const v8bf*)(Bb + (size_t)row * Kd + k0 + col);
    }
    __syncthreads();
#pragma unroll
    for (int t = 0; t < 2; ++t) {
      int s = tid + 256 * t;
      int row = s >> 2, col = (s & 3) * 8;
      *(v8bf*)&As[row * 32 + col] = ga[t];
      *(v8bf*)&Bs[row * 32 + col] = gb[t];
    }
    __syncthreads();
    v8bf af[4], bfv[4];
#pragma unroll
    for (int i = 0; i < 4; ++i) {
      af[i]  = *(const v8bf*)&As[(wm * 64 + i * 16 + lr) * 32 + q * 8];
      bfv[i] = *(const v8bf*)&Bs[(wn * 64 + i * 16 + lr) * 32 + q * 8];
    }
#pragma unroll
    for (int mt = 0; mt < 4; ++mt)
#pragma unroll
      for (int nt = 0; nt < 4; ++nt)
        acc[mt][nt] = __builtin_amdgcn_mfma_f32_16x16x32_bf16(af[mt], bfv[nt], acc[mt][nt], 0, 0, 0);
    __syncthreads();
  }
#pragma unroll
  for (int nt = 0; nt < 4; ++nt) {
    int n = n0 + wn * 64 + nt * 16 + lr;
    float bv = loadF(bias, n, f32);
#pragma unroll
    for (int mt = 0; mt < 4; ++mt)
#pragma unroll
      for (int r = 0; r < 4; ++r) {
        int m = m0 + wm * 64 + mt * 16 + q * 4 + r;
        C[(size_t)m * NG + n] = f2bf(acc[mt][nt][r] + bv);
      }
  }
}

// ---- attention energy GEMM, fused tanh-dot epilogue ----
__global__ __launch_bounds__(256) void gemm_energy(const void* __restrict__ enc,
    const bf16* __restrict__ Bt, const void* __restrict__ bias,
    const void* __restrict__ dout, size_t offH1, float* __restrict__ energy,
    const int* __restrict__ flag) {
  int f32 = *flag;
  __shared__ __align__(16) unsigned short As[128 * 32];
  __shared__ __align__(16) unsigned short Bs[128 * 32];
  const int tid = threadIdx.x;
  const int l = tid & 63;
  const int w = tid >> 6;
  const int wm = w >> 1, wn = w & 1;
  const int m0 = blockIdx.x * 128;
  const int lr = l & 15, q = l >> 4;
  v4f acc[4][4] = {};
  for (int k0 = 0; k0 < NH; k0 += 32) {
    v8bf ga[2], gb[2];
#pragma unroll
    for (int t = 0; t < 2; ++t) {
      int s = tid + 256 * t;
      int row = s >> 2, col = (s & 3) * 8;
      ga[t] = load8(enc, (size_t)(m0 + row) * NH + k0 + col, f32);
      gb[t] = *(const v8bf*)(Bt + (size_t)row * NH + k0 + col);
    }
    __syncthreads();
#pragma unroll
    for (int t = 0; t < 2; ++t) {
      int s = tid + 256 * t;
      int row = s >> 2, col = (s & 3) * 8;
      *(v8bf*)&As[row * 32 + col] = ga[t];
      *(v8bf*)&Bs[row * 32 + col] = gb[t];
    }
    __syncthreads();
    v8bf af[4], bfv[4];
#pragma unroll
    for (int i = 0; i < 4; ++i) {
      af[i]  = *(const v8bf*)&As[(wm * 64 + i * 16 + lr) * 32 + q * 8];
      bfv[i] = *(const v8bf*)&Bs[(wn * 64 + i * 16 + lr) * 32 + q * 8];
    }
#pragma unroll
    for (int mt = 0; mt < 4; ++mt)
#pragma unroll
      for (int nt = 0; nt < 4; ++nt)
        acc[mt][nt] = __builtin_amdgcn_mfma_f32_16x16x32_bf16(af[mt], bfv[nt], acc[mt][nt], 0, 0, 0);
    __syncthreads();
  }
#pragma unroll
  for (int mt = 0; mt < 4; ++mt) {
    float parts[4] = {0.f, 0.f, 0.f, 0.f};
#pragma unroll
    for (int nt = 0; nt < 4; ++nt) {
      int n = wn * 64 + nt * 16 + lr;
      float bv = loadF(bias, n, f32);
#pragma unroll
      for (int r = 0; r < 4; ++r) {
        int m = m0 + wm * 64 + mt * 16 + q * 4 + r;
        int bn = m & (BN - 1);
        float t = tanhf(acc[mt][nt][r] + bv);
        parts[r] += t * loadF(dout, offH1 + (size_t)bn * NH + n, f32);
      }
    }
#pragma unroll
    for (int r = 0; r < 4; ++r) {
      float v = parts[r];
      v += __shfl_xor(v, 1);
      v += __shfl_xor(v, 2);
      v += __shfl_xor(v, 4);
      v += __shfl_xor(v, 8);
      if (lr == 0) {
        int m = m0 + wm * 64 + mt * 16 + q * 4 + r;
        atomicAdd(&energy[m], sane(v));
      }
    }
  }
}

// ---- LSTM pointwise; c_old at element offset offCin of cell tensor ----
__global__ __launch_bounds__(128) void lstm_cell(const bf16* __restrict__ gates,
    const void* __restrict__ cell, size_t offCin, void* __restrict__ dout,
    size_t offH, size_t offC, const int* __restrict__ flag, int R) {
  int f32 = *flag;
  size_t lbn = blockIdx.x;
  size_t bn = (size_t)R + lbn;
  int h = threadIdx.x;
  const bf16* g = gates + lbn * NG;
  float iv = sane(bf2f(g[h]));
  float fv = sane(bf2f(g[NH + h]));
  float ov = sane(bf2f(g[2 * NH + h]));
  float gv = sane(bf2f(g[3 * NH + h]));
  float c = sane(loadF(cell, offCin + bn * NH + h, f32));
  float si = 1.f / (1.f + expf(-iv));
  float sf = 1.f / (1.f + expf(-fv));
  float so = 1.f / (1.f + expf(-ov));
  float cn = sf * c + si * tanhf(gv);
  float hn = so * tanhf(cn);
  storeF(dout, offC + bn * NH + h, cn, f32);
  storeF(dout, offH + bn * NH + h, hn, f32);
}

__global__ void softmax_s(const float* __restrict__ energy, float* __restrict__ attnf,
                          void* __restrict__ dout, size_t offAttn,
                          const int* __restrict__ flag) {
  int f32 = *flag;
  int bn = blockIdx.x * blockDim.x + threadIdx.x;
  float e[NS];
  float mx = -3.4e38f;
#pragma unroll
  for (int s = 0; s < NS; ++s) { e[s] = sane(energy[s * BN + bn]); mx = fmaxf(mx, e[s]); }
  float sum = 0.f;
#pragma unroll
  for (int s = 0; s < NS; ++s) { e[s] = expf(e[s] - mx); sum += e[s]; }
  float inv = 1.f / sum;
#pragma unroll
  for (int s = 0; s < NS; ++s) {
    float wv = e[s] * inv;
    attnf[(size_t)bn * NS + s] = wv;
    storeF(dout, offAttn + (size_t)bn * NS + s, wv, f32);
  }
}

__global__ __launch_bounds__(128) void context_proj(const void* __restrict__ enc,
    const float* __restrict__ attnf, void* __restrict__ dout, size_t offH1,
    const void* __restrict__ proj_w, const void* __restrict__ proj_b,
    const int* __restrict__ flag) {
  int f32 = *flag;
  int bn = blockIdx.x;
  int h = threadIdx.x;
  float ctx = 0.f;
#pragma unroll
  for (int s = 0; s < NS; ++s) {
    float aw = attnf[(size_t)bn * NS + s];
    ctx += aw * loadF(enc, ((size_t)s * BN + bn) * NH + h, f32);
  }
  float ov = loadF(dout, offH1 + (size_t)bn * NH + h, f32);
  float part = sane(ov * loadF(proj_w, h, f32) + ctx * loadF(proj_w, NH + h, f32));
#pragma unroll
  for (int mask = 1; mask < 64; mask <<= 1) part += __shfl_xor(part, mask);
  __shared__ float red[2];
  if ((h & 63) == 0) red[h >> 6] = part;
  __syncthreads();
  if (h == 0) storeF(dout, bn, red[0] + red[1] + loadF(proj_b, 0, f32), f32);
}

extern "C" void kernel_launch(void* const* d_in, const int* in_sizes, int n_in,
                              void* d_out, int out_size, void* d_ws, size_t ws_size,
                              hipStream_t stream) {
  const void* xin    = d_in[0];
  const void* enc    = d_in[1];
  const void* hidden = d_in[2];
  const void* cell   = d_in[3];
  const void* sup    = d_in[4];
  const void* w0     = d_in[5];
  const void* b0     = d_in[6];
  const void* w1     = d_in[7];
  const void* b1     = d_in[8];
  const void* aw     = d_in[9];
  const void* ab     = d_in[10];
  const void* pw     = d_in[11];
  const void* pb     = d_in[12];

  char* ws = (char*)d_ws;
  size_t off = 0;
  auto alloc = [&](size_t bytes) -> char* {
    char* p = ws + off;
    off += (bytes + 255) & ~(size_t)255;
    return p;
  };
  bf16*  feats    = (bf16*)alloc((size_t)CH * K1 * 2);
  bf16*  gates    = (bf16*)alloc((size_t)CH * NG * 2);
  float* energy   = (float*)alloc((size_t)NS * BN * 4);
  float* attnf    = (float*)alloc((size_t)BN * NS * 4);
  bf16*  Bt0      = (bf16*)alloc((size_t)NG * K0P * 2);
  bf16*  Bt1      = (bf16*)alloc((size_t)NG * K1 * 2);
  bf16*  BtA      = (bf16*)alloc((size_t)NH * NH * 2);
  int*   csr_cols = (int*)alloc((size_t)NN * MAXNNZ * 4);
  float* csr_vals = (float*)alloc((size_t)NN * MAXNNZ * 4);
  int*   csr_cnt  = (int*)alloc((size_t)NN * 4);
  int*   flag     = (int*)alloc(256);

  const size_t OFF_HS   = (size_t)BN;
  const size_t OFF_CS   = OFF_HS + (size_t)2 * BN * NH;
  const size_t OFF_ATTN = OFF_CS + (size_t)2 * BN * NH;
  const size_t OFF_H0 = OFF_HS;
  const size_t OFF_H1 = OFF_HS + (size_t)BN * NH;
  const size_t OFF_C0 = OFF_CS;
  const size_t OFF_C1 = OFF_CS + (size_t)BN * NH;
  const size_t LAYER1 = (size_t)BN * NH;   // element offset of layer 1 in hidden/cell

  detect_dtype<<<1, 256, 0, stream>>>((const unsigned short*)cell, flag);
  build_csr<<<NN, 256, 0, stream>>>(sup, csr_cols, csr_vals, csr_cnt, flag);
  pack_wt<<<NG, 256, 0, stream>>>(w0, Bt0, 387, K0P, NG, flag);
  pack_wt<<<NG, 256, 0, stream>>>(w1, Bt1, K1, K1, NG, flag);
  pack_wt<<<NH, 128, 0, stream>>>(aw, BtA, NH, NH, NH, flag);
  hipMemsetAsync(energy, 0, (size_t)NS * BN * 4, stream);

  for (int c = 0; c < NCHUNK; ++c) {
    int R = c * CH;
    diffuse0_a<<<CH, 192, 0, stream>>>(xin, hidden, csr_cols, csr_vals, csr_cnt, feats, flag, R);
    diffuse0_b<<<CH, 192, 0, stream>>>(xin, hidden, csr_cols, csr_vals, csr_cnt, feats, flag, R);
    dim3 g(CH / 128, NG / 128);
    gemm_bt<<<g, 256, 0, stream>>>(feats, Bt0, b0, gates, K0P, flag);
    lstm_cell<<<CH, 128, 0, stream>>>(gates, cell, 0, d_out, OFF_H0, OFF_C0, flag, R);
  }

  for (int c = 0; c < NCHUNK; ++c) {
    int R = c * CH;
    diffuse1_a<<<CH, 256, 0, stream>>>(d_out, OFF_H0, hidden, LAYER1,
                                       csr_cols, csr_vals, csr_cnt, feats, flag, R);
    diffuse1_b<<<CH, 256, 0, stream>>>(d_out, OFF_H0, hidden, LAYER1,
                                       csr_cols, csr_vals, csr_cnt, feats, flag, R);
    dim3 g(CH / 128, NG / 128);
    gemm_bt<<<g, 256, 0, stream>>>(feats, Bt1, b1, gates, K1, flag);
    lstm_cell<<<CH, 128, 0, stream>>>(gates, cell, LAYER1, d_out, OFF_H1, OFF_C1, flag, R);
  }

  gemm_energy<<<NS * BN / 128, 256, 0, stream>>>(enc, BtA, ab, d_out, OFF_H1, energy, flag);
  softmax_s<<<BN / 256, 256, 0, stream>>>(energy, attnf, d_out, OFF_ATTN, flag);
  context_proj<<<BN, 128, 0, stream>>>(enc, attnf, d_out, OFF_H1, pw, pb, flag);
}

// Round 4
// 1974.476 us; speedup vs baseline: 1.0626x; 1.0626x over previous
//
#include <hip/hip_runtime.h>
#include <hip/hip_bf16.h>
#include <stdint.h>

#define NB 64
#define NN 1024
#define NH 128
#define NS 12
#define BN (NB*NN)
#define D0 129
#define K0P 416
#define K1 768
#define NG 512
#define MAXNNZ 128
#define CH 16384
#define NCHUNK (BN/CH)

typedef __hip_bfloat16 bf16;
typedef float v4f __attribute__((ext_vector_type(4)));
typedef __bf16 v8bf __attribute__((ext_vector_type(8)));

__device__ __forceinline__ float bf2f(bf16 x) { return __bfloat162float(x); }
__device__ __forceinline__ bf16 f2bf(float x) { return __float2bfloat16(x); }
__device__ __forceinline__ float sane(float x) { return __builtin_isfinite(x) ? x : 0.f; }
__device__ __forceinline__ float sigf(float x) { return 1.f / (1.f + __expf(-x)); }
__device__ __forceinline__ float tanhfast(float x) { return 1.f - 2.f / (1.f + __expf(2.f * x)); }

// flagged load/store: f32 ? float data : bf16 data (flag is uniform per launch)
__device__ __forceinline__ float loadF(const void* p, size_t i, int f32) {
  return f32 ? ((const float*)p)[i] : bf2f(((const bf16*)p)[i]);
}
__device__ __forceinline__ void storeF(void* p, size_t i, float v, int f32) {
  if (f32) ((float*)p)[i] = v; else ((bf16*)p)[i] = f2bf(v);
}
// 8 elements -> v8bf; f32 path uses two float4 loads + packed converts
__device__ __forceinline__ v8bf load8(const void* p, size_t i, int f32) {
  if (f32) {
    const float4 a = *(const float4*)((const float*)p + i);
    const float4 b = *(const float4*)((const float*)p + i + 4);
    union { v8bf v; __hip_bfloat162 h[4]; } u;
    u.h[0] = __float22bfloat162_rn(make_float2(a.x, a.y));
    u.h[1] = __float22bfloat162_rn(make_float2(a.z, a.w));
    u.h[2] = __float22bfloat162_rn(make_float2(b.x, b.y));
    u.h[3] = __float22bfloat162_rn(make_float2(b.z, b.w));
    return u.v;
  }
  return *(const v8bf*)((const bf16*)p + i);
}

// dtype detector on ~N(0,1) probe: bf16 data -> even uint16s are real bf16
// (exponent 117..131 or zero); f32 data -> even uint16s are mantissa halves.
__global__ void detect_dtype(const unsigned short* __restrict__ probe, int* __restrict__ flag) {
  int t = threadIdx.x;
  unsigned short x = probe[2 * t];
  int e = (x >> 7) & 0xFF;
  int insane = !((x & 0x7FFF) == 0 || (e >= 117 && e <= 131));
  __shared__ int cnt;
  if (t == 0) cnt = 0;
  __syncthreads();
  atomicAdd(&cnt, insane);
  __syncthreads();
  if (t == 0) *flag = (cnt > 64) ? 1 : 0;
}

__global__ void build_csr(const void* __restrict__ sup, int* __restrict__ cols,
                          float* __restrict__ vals, int* __restrict__ cnt,
                          const int* __restrict__ flag) {
  int f32 = *flag;
  int n = blockIdx.x;
  __shared__ int cn;
  if (threadIdx.x == 0) cn = 0;
  __syncthreads();
  for (int m = threadIdx.x; m < NN; m += blockDim.x) {
    float v = loadF(sup, (size_t)n * NN + m, f32);
    if (v != 0.0f && __builtin_isfinite(v)) {
      int slot = atomicAdd(&cn, 1);
      if (slot < MAXNNZ) { cols[n * MAXNNZ + slot] = m; vals[n * MAXNNZ + slot] = v; }
    }
  }
  __syncthreads();
  if (threadIdx.x == 0) cnt[n] = (cn < MAXNNZ) ? cn : MAXNNZ;
}

__global__ void pack_wt(const void* __restrict__ w, bf16* __restrict__ bt,
                        int K, int Kp, int Nn, const int* __restrict__ flag) {
  int f32 = *flag;
  int n = blockIdx.x;
  for (int k = threadIdx.x; k < Kp; k += blockDim.x) {
    float v = (k < K) ? loadF(w, (size_t)k * Nn + n, f32) : 0.0f;
    bt[(size_t)n * Kp + k] = f2bf(v);
  }
}

// ---- layer 0 diffusion; R = chunk row offset (chunks are whole batches) ----
__global__ void diffuse0_a(const void* __restrict__ xin, const void* __restrict__ h0,
                           const int* __restrict__ cols, const float* __restrict__ vals,
                           const int* __restrict__ cnt, bf16* __restrict__ feats,
                           const int* __restrict__ flag, int R) {
  int f32 = *flag;
  int bn = R + blockIdx.x;
  int lbn = blockIdx.x;
  int n = bn & (NN - 1);
  int b = bn >> 10;
  int d = threadIdx.x;
  bf16* frow = feats + (size_t)lbn * K0P;
  if (d < D0) {
    float x0 = (d == 0) ? loadF(xin, bn, f32) : loadF(h0, (size_t)bn * NH + d - 1, f32);
    frow[d] = f2bf(x0);
    float acc = 0.f;
    int c = cnt[n];
    for (int j = 0; j < c; ++j) {
      int m = cols[n * MAXNNZ + j];
      float s = vals[n * MAXNNZ + j];
      int bm = (b << 10) | m;
      float xv = (d == 0) ? loadF(xin, bm, f32) : loadF(h0, (size_t)bm * NH + d - 1, f32);
      acc += s * xv;
    }
    frow[D0 + d] = f2bf(acc);
  } else if (d < D0 + (K0P - 3 * D0)) {
    frow[3 * D0 + (d - D0)] = f2bf(0.f);
  }
}

__global__ void diffuse0_b(const void* __restrict__ xin, const void* __restrict__ h0,
                           const int* __restrict__ cols, const float* __restrict__ vals,
                           const int* __restrict__ cnt, bf16* __restrict__ feats,
                           const int* __restrict__ flag, int R) {
  int f32 = *flag;
  int bn = R + blockIdx.x;
  int lbn = blockIdx.x;
  int n = bn & (NN - 1);
  int b = bn >> 10;
  int d = threadIdx.x;
  if (d >= D0) return;
  float x0 = (d == 0) ? loadF(xin, bn, f32) : loadF(h0, (size_t)bn * NH + d - 1, f32);
  float acc = -x0;
  int c = cnt[n];
  for (int j = 0; j < c; ++j) {
    int m = cols[n * MAXNNZ + j];
    float s = vals[n * MAXNNZ + j];
    int lbm = ((b << 10) | m) - R;
    float x1 = bf2f(feats[(size_t)lbm * K0P + D0 + d]);
    acc += 2.f * s * x1;
  }
  feats[(size_t)lbn * K0P + 2 * D0 + d] = f2bf(acc);
}

// ---- layer 1 diffusion ----
__global__ void diffuse1_a(const void* __restrict__ dout, size_t offH0,
                           const void* __restrict__ hidden, size_t offH1in,
                           const int* __restrict__ cols, const float* __restrict__ vals,
                           const int* __restrict__ cnt, bf16* __restrict__ feats,
                           const int* __restrict__ flag, int R) {
  int f32 = *flag;
  int bn = R + blockIdx.x;
  int lbn = blockIdx.x;
  int n = bn & (NN - 1);
  int b = bn >> 10;
  int d = threadIdx.x;   // 0..255
  bf16* frow = feats + (size_t)lbn * K1;
  float x0 = (d < NH) ? loadF(dout, offH0 + (size_t)bn * NH + d, f32)
                      : loadF(hidden, offH1in + (size_t)bn * NH + d - NH, f32);
  frow[d] = f2bf(x0);
  float acc = 0.f;
  int c = cnt[n];
  for (int j = 0; j < c; ++j) {
    int m = cols[n * MAXNNZ + j];
    float s = vals[n * MAXNNZ + j];
    size_t bm = (size_t)((b << 10) | m) * NH;
    float xv = (d < NH) ? loadF(dout, offH0 + bm + d, f32)
                        : loadF(hidden, offH1in + bm + d - NH, f32);
    acc += s * xv;
  }
  frow[256 + d] = f2bf(acc);
}

__global__ void diffuse1_b(const void* __restrict__ dout, size_t offH0,
                           const void* __restrict__ hidden, size_t offH1in,
                           const int* __restrict__ cols, const float* __restrict__ vals,
                           const int* __restrict__ cnt, bf16* __restrict__ feats,
                           const int* __restrict__ flag, int R) {
  int f32 = *flag;
  int bn = R + blockIdx.x;
  int lbn = blockIdx.x;
  int n = bn & (NN - 1);
  int b = bn >> 10;
  int d = threadIdx.x;
  float x0 = (d < NH) ? loadF(dout, offH0 + (size_t)bn * NH + d, f32)
                      : loadF(hidden, offH1in + (size_t)bn * NH + d - NH, f32);
  float acc = -x0;
  int c = cnt[n];
  for (int j = 0; j < c; ++j) {
    int m = cols[n * MAXNNZ + j];
    float s = vals[n * MAXNNZ + j];
    int lbm = ((b << 10) | m) - R;
    float x1 = bf2f(feats[(size_t)lbm * K1 + 256 + d]);
    acc += 2.f * s * x1;
  }
  feats[(size_t)lbn * K1 + 512 + d] = f2bf(acc);
}

// ---- MFMA GEMM: gates(CHx512) = feats(CHxKd) * Bt(512xKd)^T + bias ----
__global__ __launch_bounds__(256) void gemm_bt(const bf16* __restrict__ A,
    const bf16* __restrict__ Bt, const void* __restrict__ bias,
    bf16* __restrict__ C, int Kd, const int* __restrict__ flag) {
  int f32 = *flag;
  __shared__ __align__(16) unsigned short As[128 * 32];
  __shared__ __align__(16) unsigned short Bs[128 * 32];
  const int tid = threadIdx.x;
  const int l = tid & 63;
  const int w = tid >> 6;
  const int wm = w >> 1, wn = w & 1;
  const int m0 = blockIdx.x * 128;
  const int n0 = blockIdx.y * 128;
  const bf16* Ab = A + (size_t)m0 * Kd;
  const bf16* Bb = Bt + (size_t)n0 * Kd;
  const int lr = l & 15, q = l >> 4;
  v4f acc[4][4] = {};
  for (int k0 = 0; k0 < Kd; k0 += 32) {
    v8bf ga[2], gb[2];
#pragma unroll
    for (int t = 0; t < 2; ++t) {
      int s = tid + 256 * t;
      int row = s >> 2, col = (s & 3) * 8;
      ga[t] = *(const v8bf*)(Ab + (size_t)row * Kd + k0 + col);
      gb[t] = *(const v8bf*)(Bb + (size_t)row * Kd + k0 + col);
    }
    __syncthreads();
#pragma unroll
    for (int t = 0; t < 2; ++t) {
      int s = tid + 256 * t;
      int row = s >> 2, col = (s & 3) * 8;
      *(v8bf*)&As[row * 32 + col] = ga[t];
      *(v8bf*)&Bs[row * 32 + col] = gb[t];
    }
    __syncthreads();
    v8bf af[4], bfv[4];
#pragma unroll
    for (int i = 0; i < 4; ++i) {
      af[i]  = *(const v8bf*)&As[(wm * 64 + i * 16 + lr) * 32 + q * 8];
      bfv[i] = *(const v8bf*)&Bs[(wn * 64 + i * 16 + lr) * 32 + q * 8];
    }
#pragma unroll
    for (int mt = 0; mt < 4; ++mt)
#pragma unroll
      for (int nt = 0; nt < 4; ++nt)
        acc[mt][nt] = __builtin_amdgcn_mfma_f32_16x16x32_bf16(af[mt], bfv[nt], acc[mt][nt], 0, 0, 0);
    __syncthreads();
  }
#pragma unroll
  for (int nt = 0; nt < 4; ++nt) {
    int n = n0 + wn * 64 + nt * 16 + lr;
    float bv = loadF(bias, n, f32);
#pragma unroll
    for (int mt = 0; mt < 4; ++mt)
#pragma unroll
      for (int r = 0; r < 4; ++r) {
        int m = m0 + wm * 64 + mt * 16 + q * 4 + r;
        C[(size_t)m * NG + n] = f2bf(acc[mt][nt][r] + bv);
      }
  }
}

// ---- attention energy GEMM, fused tanh-dot epilogue ----
// energy[m] = sum_h tanh((enc @ attn_w)[m,h] + attn_b[h]) * h1[m % BN, h]
// B (128x128) staged in LDS once (padded stride 136); A staged per k-step with
// float4 loads + packed f32->bf16. Per-block LDS reduce -> plain store.
#define BPAD 136
__global__ __launch_bounds__(256) void gemm_energy(const void* __restrict__ enc,
    const bf16* __restrict__ Bt, const void* __restrict__ bias,
    const void* __restrict__ dout, size_t offH1, float* __restrict__ energy,
    const int* __restrict__ flag) {
  int f32 = *flag;
  __shared__ __align__(16) unsigned short As[128 * 32];
  __shared__ __align__(16) unsigned short Bsf[128 * BPAD];
  __shared__ float ered[2][128];
  const int tid = threadIdx.x;
  const int l = tid & 63;
  const int w = tid >> 6;
  const int wm = w >> 1, wn = w & 1;
  const int m0 = blockIdx.x * 128;
  const int lr = l & 15, q = l >> 4;

  // stage B once: 128x128 bf16 -> padded LDS
#pragma unroll
  for (int i = tid; i < 2048; i += 256) {
    int row = i >> 4, chunk = i & 15;
    *(v8bf*)&Bsf[row * BPAD + chunk * 8] = *(const v8bf*)(Bt + (size_t)row * NH + chunk * 8);
  }

  v4f acc[4][4] = {};
  for (int k0 = 0; k0 < NH; k0 += 32) {
    v8bf ga[2];
#pragma unroll
    for (int t = 0; t < 2; ++t) {
      int s = tid + 256 * t;
      int row = s >> 2, col = (s & 3) * 8;
      ga[t] = load8(enc, (size_t)(m0 + row) * NH + k0 + col, f32);
    }
    __syncthreads();
#pragma unroll
    for (int t = 0; t < 2; ++t) {
      int s = tid + 256 * t;
      int row = s >> 2, col = (s & 3) * 8;
      *(v8bf*)&As[row * 32 + col] = ga[t];
    }
    __syncthreads();
    v8bf af[4], bfv[4];
#pragma unroll
    for (int i = 0; i < 4; ++i) {
      af[i]  = *(const v8bf*)&As[(wm * 64 + i * 16 + lr) * 32 + q * 8];
      bfv[i] = *(const v8bf*)&Bsf[(wn * 64 + i * 16 + lr) * BPAD + k0 + q * 8];
    }
#pragma unroll
    for (int mt = 0; mt < 4; ++mt)
#pragma unroll
      for (int nt = 0; nt < 4; ++nt)
        acc[mt][nt] = __builtin_amdgcn_mfma_f32_16x16x32_bf16(af[mt], bfv[nt], acc[mt][nt], 0, 0, 0);
    __syncthreads();
  }
  // epilogue: tanh (fast), dot with out1 over h, cross-lane + cross-wave reduce
#pragma unroll
  for (int mt = 0; mt < 4; ++mt) {
    float parts[4] = {0.f, 0.f, 0.f, 0.f};
#pragma unroll
    for (int nt = 0; nt < 4; ++nt) {
      int n = wn * 64 + nt * 16 + lr;
      float bv = loadF(bias, n, f32);
#pragma unroll
      for (int r = 0; r < 4; ++r) {
        int m = m0 + wm * 64 + mt * 16 + q * 4 + r;
        int bn = m & (BN - 1);
        float t = tanhfast(acc[mt][nt][r] + bv);
        parts[r] += t * loadF(dout, offH1 + (size_t)bn * NH + n, f32);
      }
    }
#pragma unroll
    for (int r = 0; r < 4; ++r) {
      float v = parts[r];
      v += __shfl_xor(v, 1);
      v += __shfl_xor(v, 2);
      v += __shfl_xor(v, 4);
      v += __shfl_xor(v, 8);
      if (lr == 0) {
        int lm = wm * 64 + mt * 16 + q * 4 + r;
        ered[wn][lm] = v;
      }
    }
  }
  __syncthreads();
  if (tid < 128) energy[m0 + tid] = sane(ered[0][tid] + ered[1][tid]);
}

// ---- LSTM pointwise ----
__global__ __launch_bounds__(128) void lstm_cell(const bf16* __restrict__ gates,
    const void* __restrict__ cell, size_t offCin, void* __restrict__ dout,
    size_t offH, size_t offC, const int* __restrict__ flag, int R) {
  int f32 = *flag;
  size_t lbn = blockIdx.x;
  size_t bn = (size_t)R + lbn;
  int h = threadIdx.x;
  const bf16* g = gates + lbn * NG;
  float iv = sane(bf2f(g[h]));
  float fv = sane(bf2f(g[NH + h]));
  float ov = sane(bf2f(g[2 * NH + h]));
  float gv = sane(bf2f(g[3 * NH + h]));
  float c = sane(loadF(cell, offCin + bn * NH + h, f32));
  float cn = sigf(fv) * c + sigf(iv) * tanhfast(gv);
  float hn = sigf(ov) * tanhfast(cn);
  storeF(dout, offC + bn * NH + h, cn, f32);
  storeF(dout, offH + bn * NH + h, hn, f32);
}

__global__ void softmax_s(const float* __restrict__ energy, float* __restrict__ attnf,
                          void* __restrict__ dout, size_t offAttn,
                          const int* __restrict__ flag) {
  int f32 = *flag;
  int bn = blockIdx.x * blockDim.x + threadIdx.x;
  float e[NS];
  float mx = -3.4e38f;
#pragma unroll
  for (int s = 0; s < NS; ++s) { e[s] = sane(energy[s * BN + bn]); mx = fmaxf(mx, e[s]); }
  float sum = 0.f;
#pragma unroll
  for (int s = 0; s < NS; ++s) { e[s] = __expf(e[s] - mx); sum += e[s]; }
  float inv = 1.f / sum;
#pragma unroll
  for (int s = 0; s < NS; ++s) {
    float wv = e[s] * inv;
    attnf[(size_t)bn * NS + s] = wv;
    storeF(dout, offAttn + (size_t)bn * NS + s, wv, f32);
  }
}

// ---- context gather + projection; 2 rows per block ----
__global__ __launch_bounds__(256) void context_proj(const void* __restrict__ enc,
    const float* __restrict__ attnf, void* __restrict__ dout, size_t offH1,
    const void* __restrict__ proj_w, const void* __restrict__ proj_b,
    const int* __restrict__ flag) {
  int f32 = *flag;
  int sub = threadIdx.x >> 7;           // 0 or 1
  int h = threadIdx.x & 127;
  int bn = blockIdx.x * 2 + sub;
  float ctx = 0.f;
#pragma unroll
  for (int s = 0; s < NS; ++s) {
    float aw = attnf[(size_t)bn * NS + s];
    ctx += aw * loadF(enc, ((size_t)s * BN + bn) * NH + h, f32);
  }
  float ov = loadF(dout, offH1 + (size_t)bn * NH + h, f32);
  float part = sane(ov * loadF(proj_w, h, f32) + ctx * loadF(proj_w, NH + h, f32));
#pragma unroll
  for (int mask = 1; mask < 64; mask <<= 1) part += __shfl_xor(part, mask);
  __shared__ float red[4];
  if ((threadIdx.x & 63) == 0) red[threadIdx.x >> 6] = part;
  __syncthreads();
  if (h == 0) storeF(dout, bn, red[sub * 2] + red[sub * 2 + 1] + loadF(proj_b, 0, f32), f32);
}

extern "C" void kernel_launch(void* const* d_in, const int* in_sizes, int n_in,
                              void* d_out, int out_size, void* d_ws, size_t ws_size,
                              hipStream_t stream) {
  const void* xin    = d_in[0];
  const void* enc    = d_in[1];
  const void* hidden = d_in[2];
  const void* cell   = d_in[3];
  const void* sup    = d_in[4];
  const void* w0     = d_in[5];
  const void* b0     = d_in[6];
  const void* w1     = d_in[7];
  const void* b1     = d_in[8];
  const void* aw     = d_in[9];
  const void* ab     = d_in[10];
  const void* pw     = d_in[11];
  const void* pb     = d_in[12];

  char* ws = (char*)d_ws;
  size_t off = 0;
  auto alloc = [&](size_t bytes) -> char* {
    char* p = ws + off;
    off += (bytes + 255) & ~(size_t)255;
    return p;
  };
  bf16*  feats    = (bf16*)alloc((size_t)CH * K1 * 2);
  bf16*  gates    = (bf16*)alloc((size_t)CH * NG * 2);
  float* energy   = (float*)alloc((size_t)NS * BN * 4);
  float* attnf    = (float*)alloc((size_t)BN * NS * 4);
  bf16*  Bt0      = (bf16*)alloc((size_t)NG * K0P * 2);
  bf16*  Bt1      = (bf16*)alloc((size_t)NG * K1 * 2);
  bf16*  BtA      = (bf16*)alloc((size_t)NH * NH * 2);
  int*   csr_cols = (int*)alloc((size_t)NN * MAXNNZ * 4);
  float* csr_vals = (float*)alloc((size_t)NN * MAXNNZ * 4);
  int*   csr_cnt  = (int*)alloc((size_t)NN * 4);
  int*   flag     = (int*)alloc(256);

  const size_t OFF_HS   = (size_t)BN;
  const size_t OFF_CS   = OFF_HS + (size_t)2 * BN * NH;
  const size_t OFF_ATTN = OFF_CS + (size_t)2 * BN * NH;
  const size_t OFF_H0 = OFF_HS;
  const size_t OFF_H1 = OFF_HS + (size_t)BN * NH;
  const size_t OFF_C0 = OFF_CS;
  const size_t OFF_C1 = OFF_CS + (size_t)BN * NH;
  const size_t LAYER1 = (size_t)BN * NH;

  detect_dtype<<<1, 256, 0, stream>>>((const unsigned short*)cell, flag);
  build_csr<<<NN, 256, 0, stream>>>(sup, csr_cols, csr_vals, csr_cnt, flag);
  pack_wt<<<NG, 256, 0, stream>>>(w0, Bt0, 387, K0P, NG, flag);
  pack_wt<<<NG, 256, 0, stream>>>(w1, Bt1, K1, K1, NG, flag);
  pack_wt<<<NH, 128, 0, stream>>>(aw, BtA, NH, NH, NH, flag);

  for (int c = 0; c < NCHUNK; ++c) {
    int R = c * CH;
    diffuse0_a<<<CH, 192, 0, stream>>>(xin, hidden, csr_cols, csr_vals, csr_cnt, feats, flag, R);
    diffuse0_b<<<CH, 192, 0, stream>>>(xin, hidden, csr_cols, csr_vals, csr_cnt, feats, flag, R);
    dim3 g(CH / 128, NG / 128);
    gemm_bt<<<g, 256, 0, stream>>>(feats, Bt0, b0, gates, K0P, flag);
    lstm_cell<<<CH, 128, 0, stream>>>(gates, cell, 0, d_out, OFF_H0, OFF_C0, flag, R);
  }

  for (int c = 0; c < NCHUNK; ++c) {
    int R = c * CH;
    diffuse1_a<<<CH, 256, 0, stream>>>(d_out, OFF_H0, hidden, LAYER1,
                                       csr_cols, csr_vals, csr_cnt, feats, flag, R);
    diffuse1_b<<<CH, 256, 0, stream>>>(d_out, OFF_H0, hidden, LAYER1,
                                       csr_cols, csr_vals, csr_cnt, feats, flag, R);
    dim3 g(CH / 128, NG / 128);
    gemm_bt<<<g, 256, 0, stream>>>(feats, Bt1, b1, gates, K1, flag);
    lstm_cell<<<CH, 128, 0, stream>>>(gates, cell, LAYER1, d_out, OFF_H1, OFF_C1, flag, R);
  }

  gemm_energy<<<NS * BN / 128, 256, 0, stream>>>(enc, BtA, ab, d_out, OFF_H1, energy, flag);
  softmax_s<<<BN / 256, 256, 0, stream>>>(energy, attnf, d_out, OFF_ATTN, flag);
  context_proj<<<BN / 2, 256, 0, stream>>>(enc, attnf, d_out, OFF_H1, pw, pb, flag);
}